// Round 1
// baseline (671.084 us; speedup 1.0000x reference)
//
#include <hip/hip_runtime.h>

#define N_NODES 50000
#define N_EDGES 800000
#define D 128

// ---------------------------------------------------------------------------
// K1: degree histogram (int atomics, random-address; ~800k atomics total)
// ---------------------------------------------------------------------------
__global__ void k_degree(const int* __restrict__ dst, int* __restrict__ deg) {
    int e = blockIdx.x * 256 + threadIdx.x;
    if (e < N_EDGES) atomicAdd(&deg[dst[e]], 1);
}

// ---------------------------------------------------------------------------
// K2: single-block exclusive scan of degrees -> row_off[N+1]; also rcp_deg
// ---------------------------------------------------------------------------
__global__ __launch_bounds__(1024) void k_scan(const int* __restrict__ deg,
                                               int* __restrict__ row_off,
                                               float* __restrict__ rcp) {
    __shared__ int sdata[1024];
    int base = 0;
    for (int chunk = 0; chunk < N_NODES; chunk += 1024) {
        int i = chunk + (int)threadIdx.x;
        int v = (i < N_NODES) ? deg[i] : 0;
        if (i < N_NODES) rcp[i] = 1.0f / (float)max(v, 1);
        sdata[threadIdx.x] = v;
        __syncthreads();
        // Hillis-Steele inclusive scan
        for (int off = 1; off < 1024; off <<= 1) {
            int t = (threadIdx.x >= (unsigned)off) ? sdata[threadIdx.x - off] : 0;
            __syncthreads();
            sdata[threadIdx.x] += t;
            __syncthreads();
        }
        int incl = sdata[threadIdx.x];
        int total = sdata[1023];
        if (i < N_NODES) row_off[i] = base + incl - v;  // exclusive
        base += total;
        __syncthreads();
    }
    if (threadIdx.x == 0) row_off[N_NODES] = base;  // == N_EDGES
}

// ---------------------------------------------------------------------------
// K3: CSR fill: csr[row_off[dst]+slot] = src
// ---------------------------------------------------------------------------
__global__ void k_fill(const int* __restrict__ src, const int* __restrict__ dst,
                       const int* __restrict__ row_off, int* __restrict__ fill,
                       int* __restrict__ csr) {
    int e = blockIdx.x * 256 + threadIdx.x;
    if (e < N_EDGES) {
        int d = dst[e];
        int p = row_off[d] + atomicAdd(&fill[d], 1);
        csr[p] = src[e];
    }
}

// ---------------------------------------------------------------------------
// K4: dual GEMM: blockIdx.y==0 -> hs = h@W_self + b ; blockIdx.y==1 -> hn = h@W_neigh
// Block: 256 threads; tile 64 rows x 128 cols; K staged in chunks of 32.
// Per-thread: 4 rows x 8 cols register accumulators.
// ---------------------------------------------------------------------------
__global__ __launch_bounds__(256) void k_gemm_dual(
        const float* __restrict__ h,
        const float* __restrict__ Wself, const float* __restrict__ Wneigh,
        const float* __restrict__ bias,
        float* __restrict__ hs, float* __restrict__ hn) {
    const bool is_self = (blockIdx.y == 0);
    const float* __restrict__ W = is_self ? Wself : Wneigh;
    float* __restrict__ out = is_self ? hs : hn;

    const int row0 = blockIdx.x * 64;
    __shared__ __align__(16) float Wl[32][128];  // 16 KB
    __shared__ __align__(16) float hl[64][36];   // padded row stride (144 B, 16B-aligned)

    const int tc = threadIdx.x & 15;   // col group: cols tc*8 .. tc*8+7
    const int tr = threadIdx.x >> 4;   // row group: rows tr*4 .. tr*4+3

    float acc[4][8];
#pragma unroll
    for (int r = 0; r < 4; ++r)
#pragma unroll
        for (int c = 0; c < 8; ++c) acc[r][c] = 0.0f;

    for (int k0 = 0; k0 < D; k0 += 32) {
        // stage W chunk [32 x 128] : 1024 float4, 4 per thread
#pragma unroll
        for (int j = 0; j < 4; ++j) {
            int t = (int)threadIdx.x + j * 256;   // 0..1023
            int kk = t >> 5, c4 = t & 31;
            float4 v = ((const float4*)&W[(size_t)(k0 + kk) * D])[c4];
            ((float4*)&Wl[kk][0])[c4] = v;
        }
        // stage h chunk [64 rows x 32] : 512 float4, 2 per thread
#pragma unroll
        for (int j = 0; j < 2; ++j) {
            int t = (int)threadIdx.x + j * 256;   // 0..511
            int r = t >> 3, c4 = t & 7;
            int row = row0 + r;
            if (row >= N_NODES) row = N_NODES - 1;  // clamp (dup load, stores guarded)
            float4 v = ((const float4*)&h[(size_t)row * D + k0])[c4];
            *(float4*)&hl[r][c4 * 4] = v;
        }
        __syncthreads();

#pragma unroll
        for (int kk = 0; kk < 32; ++kk) {
            float a[4];
#pragma unroll
            for (int r = 0; r < 4; ++r) a[r] = hl[tr * 4 + r][kk];
            float4 w0 = *(const float4*)&Wl[kk][tc * 8];
            float4 w1 = *(const float4*)&Wl[kk][tc * 8 + 4];
            float w[8] = {w0.x, w0.y, w0.z, w0.w, w1.x, w1.y, w1.z, w1.w};
#pragma unroll
            for (int r = 0; r < 4; ++r)
#pragma unroll
                for (int c = 0; c < 8; ++c) acc[r][c] = fmaf(a[r], w[c], acc[r][c]);
        }
        __syncthreads();
    }

    // epilogue
    float bv[8];
#pragma unroll
    for (int c = 0; c < 8; ++c) bv[c] = is_self ? bias[tc * 8 + c] : 0.0f;
#pragma unroll
    for (int r = 0; r < 4; ++r) {
        int row = row0 + tr * 4 + r;
        if (row < N_NODES) {
            float4 o0 = {acc[r][0] + bv[0], acc[r][1] + bv[1],
                         acc[r][2] + bv[2], acc[r][3] + bv[3]};
            float4 o1 = {acc[r][4] + bv[4], acc[r][5] + bv[5],
                         acc[r][6] + bv[6], acc[r][7] + bv[7]};
            ((float4*)&out[(size_t)row * D])[tc * 2 + 0] = o0;
            ((float4*)&out[(size_t)row * D])[tc * 2 + 1] = o1;
        }
    }
}

// ---------------------------------------------------------------------------
// K5: aggregate: out[v] = act( hs[v] + rcp[v] * sum_{u in csr(v)} hn[u] )
// One wave per node; lane covers 2 cols via float2 (512 B coalesced / nbr).
// ---------------------------------------------------------------------------
__global__ __launch_bounds__(256) void k_agg(
        const float* __restrict__ hs, const float* __restrict__ hn,
        const int* __restrict__ row_off, const int* __restrict__ csr,
        const float* __restrict__ rcp, float* __restrict__ out, int relu) {
    int v = blockIdx.x * 4 + (int)(threadIdx.x >> 6);  // node per wave
    int lane = threadIdx.x & 63;
    if (v >= N_NODES) return;
    int beg = row_off[v];
    int end = row_off[v + 1];
    float ax = 0.0f, ay = 0.0f;
    for (int j = beg; j < end; ++j) {
        int u = csr[j];
        float2 x = *(const float2*)&hn[(size_t)u * D + lane * 2];
        ax += x.x;
        ay += x.y;
    }
    float r = rcp[v];
    float2 s = *(const float2*)&hs[(size_t)v * D + lane * 2];
    float ox = fmaf(ax, r, s.x);
    float oy = fmaf(ay, r, s.y);
    if (relu) { ox = fmaxf(ox, 0.0f); oy = fmaxf(oy, 0.0f); }
    *(float2*)&out[(size_t)v * D + lane * 2] = make_float2(ox, oy);
}

// ---------------------------------------------------------------------------
extern "C" void kernel_launch(void* const* d_in, const int* in_sizes, int n_in,
                              void* d_out, int out_size, void* d_ws, size_t ws_size,
                              hipStream_t stream) {
    const float* features = (const float*)d_in[0];
    const int*   edge_src = (const int*)d_in[1];
    const int*   edge_dst = (const int*)d_in[2];
    const float* Wself[3] = {(const float*)d_in[3], (const float*)d_in[6], (const float*)d_in[9]};
    const float* Wngh[3]  = {(const float*)d_in[4], (const float*)d_in[7], (const float*)d_in[10]};
    const float* bias[3]  = {(const float*)d_in[5], (const float*)d_in[8], (const float*)d_in[11]};
    float* out = (float*)d_out;

    // workspace layout (256B-aligned chunks)
    char* ws = (char*)d_ws;
    size_t off = 0;
    auto alloc = [&](size_t bytes) {
        char* p = ws + off;
        off += (bytes + 255) & ~(size_t)255;
        return p;
    };
    int*   deg     = (int*)alloc(N_NODES * sizeof(int));
    int*   fill    = (int*)alloc(N_NODES * sizeof(int));
    int*   row_off = (int*)alloc((N_NODES + 1) * sizeof(int));
    float* rcp     = (float*)alloc(N_NODES * sizeof(float));
    int*   csr     = (int*)alloc(N_EDGES * sizeof(int));
    float* hs      = (float*)alloc((size_t)N_NODES * D * sizeof(float));
    float* hn      = (float*)alloc((size_t)N_NODES * D * sizeof(float));
    float* hb      = (float*)alloc((size_t)N_NODES * D * sizeof(float));

    // zero deg + fill (adjacent allocations)
    hipMemsetAsync(deg, 0, ((N_NODES * sizeof(int) + 255) & ~(size_t)255) * 2, stream);

    // CSR build
    k_degree<<<(N_EDGES + 255) / 256, 256, 0, stream>>>(edge_dst, deg);
    k_scan<<<1, 1024, 0, stream>>>(deg, row_off, rcp);
    k_fill<<<(N_EDGES + 255) / 256, 256, 0, stream>>>(edge_src, edge_dst, row_off, fill, csr);

    const int gemm_gx = (N_NODES + 63) / 64;
    const int agg_gx  = (N_NODES + 3) / 4;

    // layer 0: features -> hb (relu)
    k_gemm_dual<<<dim3(gemm_gx, 2), 256, 0, stream>>>(features, Wself[0], Wngh[0], bias[0], hs, hn);
    k_agg<<<agg_gx, 256, 0, stream>>>(hs, hn, row_off, csr, rcp, hb, 1);
    // layer 1: hb -> hb (relu)
    k_gemm_dual<<<dim3(gemm_gx, 2), 256, 0, stream>>>(hb, Wself[1], Wngh[1], bias[1], hs, hn);
    k_agg<<<agg_gx, 256, 0, stream>>>(hs, hn, row_off, csr, rcp, hb, 1);
    // layer 2: hb -> out (no act)
    k_gemm_dual<<<dim3(gemm_gx, 2), 256, 0, stream>>>(hb, Wself[2], Wngh[2], bias[2], hs, hn);
    k_agg<<<agg_gx, 256, 0, stream>>>(hs, hn, row_off, csr, rcp, out, 0);
}

// Round 2
// 577.429 us; speedup vs baseline: 1.1622x; 1.1622x over previous
//
#include <hip/hip_runtime.h>

#define N_NODES 50000
#define N_EDGES 800000
#define D 128
#define NB ((N_NODES + 255) / 256)   // 196 blocks for node-indexed scans

// ---------------------------------------------------------------------------
// K1: degree histogram (int atomics, random-address; ~800k atomics total)
// ---------------------------------------------------------------------------
__global__ void k_degree(const int* __restrict__ dst, int* __restrict__ deg) {
    int e = blockIdx.x * 256 + threadIdx.x;
    if (e < N_EDGES) atomicAdd(&deg[dst[e]], 1);
}

// ---------------------------------------------------------------------------
// K2a: per-block scan: row_off[i] = exclusive prefix within block,
//      partial[b] = block total, rcp[i] = 1/max(deg,1)
// ---------------------------------------------------------------------------
__global__ __launch_bounds__(256) void k_scan1(const int* __restrict__ deg,
                                               int* __restrict__ row_off,
                                               int* __restrict__ partial,
                                               float* __restrict__ rcp) {
    __shared__ int s[256];
    int i = blockIdx.x * 256 + (int)threadIdx.x;
    int v = (i < N_NODES) ? deg[i] : 0;
    if (i < N_NODES) rcp[i] = 1.0f / (float)max(v, 1);
    s[threadIdx.x] = v;
    __syncthreads();
#pragma unroll
    for (int off = 1; off < 256; off <<= 1) {
        int t = (threadIdx.x >= (unsigned)off) ? s[threadIdx.x - off] : 0;
        __syncthreads();
        s[threadIdx.x] += t;
        __syncthreads();
    }
    if (i < N_NODES) row_off[i] = s[threadIdx.x] - v;   // block-local exclusive
    if (threadIdx.x == 255) partial[blockIdx.x] = s[255];
}

// ---------------------------------------------------------------------------
// K2b: scan the 196 block partials (one block; NB <= 256)
// ---------------------------------------------------------------------------
__global__ __launch_bounds__(256) void k_scan2(const int* __restrict__ partial,
                                               int* __restrict__ partial_pref) {
    __shared__ int s[256];
    int v = ((int)threadIdx.x < NB) ? partial[threadIdx.x] : 0;
    s[threadIdx.x] = v;
    __syncthreads();
#pragma unroll
    for (int off = 1; off < 256; off <<= 1) {
        int t = (threadIdx.x >= (unsigned)off) ? s[threadIdx.x - off] : 0;
        __syncthreads();
        s[threadIdx.x] += t;
        __syncthreads();
    }
    if ((int)threadIdx.x < NB) partial_pref[threadIdx.x] = s[threadIdx.x] - v;
}

// ---------------------------------------------------------------------------
// K2c: add block offsets in place; row_off[N] = E (total degree is exactly E)
// ---------------------------------------------------------------------------
__global__ __launch_bounds__(256) void k_scan3(int* __restrict__ row_off,
                                               const int* __restrict__ partial_pref) {
    int i = blockIdx.x * 256 + (int)threadIdx.x;
    if (i < N_NODES) row_off[i] += partial_pref[blockIdx.x];
    if (i == 0) row_off[N_NODES] = N_EDGES;
}

// ---------------------------------------------------------------------------
// K3: CSR fill: csr[row_off[dst]+slot] = src
// ---------------------------------------------------------------------------
__global__ void k_fill(const int* __restrict__ src, const int* __restrict__ dst,
                       const int* __restrict__ row_off, int* __restrict__ fill,
                       int* __restrict__ csr) {
    int e = blockIdx.x * 256 + threadIdx.x;
    if (e < N_EDGES) {
        int d = dst[e];
        int p = row_off[d] + atomicAdd(&fill[d], 1);
        csr[p] = src[e];
    }
}

// ---------------------------------------------------------------------------
// K4: dual GEMM: blockIdx.y==0 -> hs = h@W_self + b ; blockIdx.y==1 -> hn = h@W_neigh
// Block: 256 threads; tile 64 rows x 128 cols; K staged in chunks of 32.
// Per-thread: 4 rows x 8 cols register accumulators.
// ---------------------------------------------------------------------------
__global__ __launch_bounds__(256) void k_gemm_dual(
        const float* __restrict__ h,
        const float* __restrict__ Wself, const float* __restrict__ Wneigh,
        const float* __restrict__ bias,
        float* __restrict__ hs, float* __restrict__ hn) {
    const bool is_self = (blockIdx.y == 0);
    const float* __restrict__ W = is_self ? Wself : Wneigh;
    float* __restrict__ out = is_self ? hs : hn;

    const int row0 = blockIdx.x * 64;
    __shared__ __align__(16) float Wl[32][128];  // 16 KB
    __shared__ __align__(16) float hl[64][36];   // padded row stride (144 B, 16B-aligned)

    const int tc = threadIdx.x & 15;   // col group: cols tc*8 .. tc*8+7
    const int tr = threadIdx.x >> 4;   // row group: rows tr*4 .. tr*4+3

    float acc[4][8];
#pragma unroll
    for (int r = 0; r < 4; ++r)
#pragma unroll
        for (int c = 0; c < 8; ++c) acc[r][c] = 0.0f;

    for (int k0 = 0; k0 < D; k0 += 32) {
        // stage W chunk [32 x 128] : 1024 float4, 4 per thread
#pragma unroll
        for (int j = 0; j < 4; ++j) {
            int t = (int)threadIdx.x + j * 256;   // 0..1023
            int kk = t >> 5, c4 = t & 31;
            float4 v = ((const float4*)&W[(size_t)(k0 + kk) * D])[c4];
            ((float4*)&Wl[kk][0])[c4] = v;
        }
        // stage h chunk [64 rows x 32] : 512 float4, 2 per thread
#pragma unroll
        for (int j = 0; j < 2; ++j) {
            int t = (int)threadIdx.x + j * 256;   // 0..511
            int r = t >> 3, c4 = t & 7;
            int row = row0 + r;
            if (row >= N_NODES) row = N_NODES - 1;  // clamp (dup load, stores guarded)
            float4 v = ((const float4*)&h[(size_t)row * D + k0])[c4];
            *(float4*)&hl[r][c4 * 4] = v;
        }
        __syncthreads();

#pragma unroll
        for (int kk = 0; kk < 32; ++kk) {
            float a[4];
#pragma unroll
            for (int r = 0; r < 4; ++r) a[r] = hl[tr * 4 + r][kk];
            float4 w0 = *(const float4*)&Wl[kk][tc * 8];
            float4 w1 = *(const float4*)&Wl[kk][tc * 8 + 4];
            float w[8] = {w0.x, w0.y, w0.z, w0.w, w1.x, w1.y, w1.z, w1.w};
#pragma unroll
            for (int r = 0; r < 4; ++r)
#pragma unroll
                for (int c = 0; c < 8; ++c) acc[r][c] = fmaf(a[r], w[c], acc[r][c]);
        }
        __syncthreads();
    }

    // epilogue
    float bv[8];
#pragma unroll
    for (int c = 0; c < 8; ++c) bv[c] = is_self ? bias[tc * 8 + c] : 0.0f;
#pragma unroll
    for (int r = 0; r < 4; ++r) {
        int row = row0 + tr * 4 + r;
        if (row < N_NODES) {
            float4 o0 = {acc[r][0] + bv[0], acc[r][1] + bv[1],
                         acc[r][2] + bv[2], acc[r][3] + bv[3]};
            float4 o1 = {acc[r][4] + bv[4], acc[r][5] + bv[5],
                         acc[r][6] + bv[6], acc[r][7] + bv[7]};
            ((float4*)&out[(size_t)row * D])[tc * 2 + 0] = o0;
            ((float4*)&out[(size_t)row * D])[tc * 2 + 1] = o1;
        }
    }
}

// ---------------------------------------------------------------------------
// K5: aggregate: out[v] = act( hs[v] + rcp[v] * sum_{u in csr(v)} hn[u] )
// One wave per node; lane covers 2 cols via float2 (512 B coalesced / nbr).
// ---------------------------------------------------------------------------
__global__ __launch_bounds__(256) void k_agg(
        const float* __restrict__ hs, const float* __restrict__ hn,
        const int* __restrict__ row_off, const int* __restrict__ csr,
        const float* __restrict__ rcp, float* __restrict__ out, int relu) {
    int v = blockIdx.x * 4 + (int)(threadIdx.x >> 6);  // node per wave
    int lane = threadIdx.x & 63;
    if (v >= N_NODES) return;
    int beg = row_off[v];
    int end = row_off[v + 1];
    float ax = 0.0f, ay = 0.0f;
    for (int j = beg; j < end; ++j) {
        int u = csr[j];
        float2 x = *(const float2*)&hn[(size_t)u * D + lane * 2];
        ax += x.x;
        ay += x.y;
    }
    float r = rcp[v];
    float2 s = *(const float2*)&hs[(size_t)v * D + lane * 2];
    float ox = fmaf(ax, r, s.x);
    float oy = fmaf(ay, r, s.y);
    if (relu) { ox = fmaxf(ox, 0.0f); oy = fmaxf(oy, 0.0f); }
    *(float2*)&out[(size_t)v * D + lane * 2] = make_float2(ox, oy);
}

// ---------------------------------------------------------------------------
extern "C" void kernel_launch(void* const* d_in, const int* in_sizes, int n_in,
                              void* d_out, int out_size, void* d_ws, size_t ws_size,
                              hipStream_t stream) {
    const float* features = (const float*)d_in[0];
    const int*   edge_src = (const int*)d_in[1];
    const int*   edge_dst = (const int*)d_in[2];
    const float* Wself[3] = {(const float*)d_in[3], (const float*)d_in[6], (const float*)d_in[9]};
    const float* Wngh[3]  = {(const float*)d_in[4], (const float*)d_in[7], (const float*)d_in[10]};
    const float* bias[3]  = {(const float*)d_in[5], (const float*)d_in[8], (const float*)d_in[11]};
    float* out = (float*)d_out;

    // workspace layout (256B-aligned chunks)
    char* ws = (char*)d_ws;
    size_t off = 0;
    auto alloc = [&](size_t bytes) {
        char* p = ws + off;
        off += (bytes + 255) & ~(size_t)255;
        return p;
    };
    int*   deg     = (int*)alloc(N_NODES * sizeof(int));
    int*   fill    = (int*)alloc(N_NODES * sizeof(int));
    int*   row_off = (int*)alloc((N_NODES + 1) * sizeof(int));
    float* rcp     = (float*)alloc(N_NODES * sizeof(float));
    int*   csr     = (int*)alloc(N_EDGES * sizeof(int));
    float* hs      = (float*)alloc((size_t)N_NODES * D * sizeof(float));
    float* hn      = (float*)alloc((size_t)N_NODES * D * sizeof(float));
    float* hb      = (float*)alloc((size_t)N_NODES * D * sizeof(float));
    int*   partial = (int*)alloc(NB * sizeof(int));
    int*   ppref   = (int*)alloc(NB * sizeof(int));

    // zero deg + fill (adjacent allocations)
    hipMemsetAsync(deg, 0, ((N_NODES * sizeof(int) + 255) & ~(size_t)255) * 2, stream);

    // CSR build
    k_degree<<<(N_EDGES + 255) / 256, 256, 0, stream>>>(edge_dst, deg);
    k_scan1<<<NB, 256, 0, stream>>>(deg, row_off, partial, rcp);
    k_scan2<<<1, 256, 0, stream>>>(partial, ppref);
    k_scan3<<<NB, 256, 0, stream>>>(row_off, ppref);
    k_fill<<<(N_EDGES + 255) / 256, 256, 0, stream>>>(edge_src, edge_dst, row_off, fill, csr);

    const int gemm_gx = (N_NODES + 63) / 64;
    const int agg_gx  = (N_NODES + 3) / 4;

    // layer 0: features -> hb (relu)
    k_gemm_dual<<<dim3(gemm_gx, 2), 256, 0, stream>>>(features, Wself[0], Wngh[0], bias[0], hs, hn);
    k_agg<<<agg_gx, 256, 0, stream>>>(hs, hn, row_off, csr, rcp, hb, 1);
    // layer 1: hb -> hb (relu)
    k_gemm_dual<<<dim3(gemm_gx, 2), 256, 0, stream>>>(hb, Wself[1], Wngh[1], bias[1], hs, hn);
    k_agg<<<agg_gx, 256, 0, stream>>>(hs, hn, row_off, csr, rcp, hb, 1);
    // layer 2: hb -> out (no act)
    k_gemm_dual<<<dim3(gemm_gx, 2), 256, 0, stream>>>(hb, Wself[2], Wngh[2], bias[2], hs, hn);
    k_agg<<<agg_gx, 256, 0, stream>>>(hs, hn, row_off, csr, rcp, out, 0);
}

// Round 4
// 355.209 us; speedup vs baseline: 1.8893x; 1.6256x over previous
//
#include <hip/hip_runtime.h>

#define N_NODES 50000
#define N_EDGES 800000
#define D 128
#define NB ((N_NODES + 255) / 256)   // 196 blocks for node-indexed scans
#define LDA 136                      // LDS row stride in ushorts (128 + 8 pad)

typedef unsigned short u16;
typedef unsigned int   u32;
typedef short bf16x8 __attribute__((ext_vector_type(8)));
typedef float f32x16 __attribute__((ext_vector_type(16)));

// f32 -> bf16 (round-to-nearest-even)
__device__ __forceinline__ u16 f2b(float x) {
    union { float f; u32 u; } c; c.f = x;
    u32 r = c.u + 0x7FFFu + ((c.u >> 16) & 1u);
    return (u16)(r >> 16);
}
__device__ __forceinline__ float b2f(u16 u) {
    union { u32 u; float f; } c; c.u = ((u32)u) << 16;
    return c.f;
}

// ---------------------------------------------------------------------------
// K1: degree histogram
// ---------------------------------------------------------------------------
__global__ void k_degree(const int* __restrict__ dst, int* __restrict__ deg) {
    int e = blockIdx.x * 256 + threadIdx.x;
    if (e < N_EDGES) atomicAdd(&deg[dst[e]], 1);
}

// ---------------------------------------------------------------------------
// K2a/b/c: 3-phase scan for row_off
// ---------------------------------------------------------------------------
__global__ __launch_bounds__(256) void k_scan1(const int* __restrict__ deg,
                                               int* __restrict__ row_off,
                                               int* __restrict__ partial,
                                               float* __restrict__ rcp) {
    __shared__ int s[256];
    int i = blockIdx.x * 256 + (int)threadIdx.x;
    int v = (i < N_NODES) ? deg[i] : 0;
    if (i < N_NODES) rcp[i] = 1.0f / (float)max(v, 1);
    s[threadIdx.x] = v;
    __syncthreads();
#pragma unroll
    for (int off = 1; off < 256; off <<= 1) {
        int t = (threadIdx.x >= (unsigned)off) ? s[threadIdx.x - off] : 0;
        __syncthreads();
        s[threadIdx.x] += t;
        __syncthreads();
    }
    if (i < N_NODES) row_off[i] = s[threadIdx.x] - v;
    if (threadIdx.x == 255) partial[blockIdx.x] = s[255];
}

__global__ __launch_bounds__(256) void k_scan2(const int* __restrict__ partial,
                                               int* __restrict__ partial_pref) {
    __shared__ int s[256];
    int v = ((int)threadIdx.x < NB) ? partial[threadIdx.x] : 0;
    s[threadIdx.x] = v;
    __syncthreads();
#pragma unroll
    for (int off = 1; off < 256; off <<= 1) {
        int t = (threadIdx.x >= (unsigned)off) ? s[threadIdx.x - off] : 0;
        __syncthreads();
        s[threadIdx.x] += t;
        __syncthreads();
    }
    if ((int)threadIdx.x < NB) partial_pref[threadIdx.x] = s[threadIdx.x] - v;
}

__global__ __launch_bounds__(256) void k_scan3(int* __restrict__ row_off,
                                               const int* __restrict__ partial_pref) {
    int i = blockIdx.x * 256 + (int)threadIdx.x;
    if (i < N_NODES) row_off[i] += partial_pref[blockIdx.x];
    if (i == 0) row_off[N_NODES] = N_EDGES;
}

// ---------------------------------------------------------------------------
// K3: CSR fill
// ---------------------------------------------------------------------------
__global__ void k_fill(const int* __restrict__ src, const int* __restrict__ dst,
                       const int* __restrict__ row_off, int* __restrict__ fill,
                       int* __restrict__ csr) {
    int e = blockIdx.x * 256 + threadIdx.x;
    if (e < N_EDGES) {
        int d = dst[e];
        int p = row_off[d] + atomicAdd(&fill[d], 1);
        csr[p] = src[e];
    }
}

// ---------------------------------------------------------------------------
// K4: cast features f32 -> bf16 (8 elems/thread)
// ---------------------------------------------------------------------------
__global__ __launch_bounds__(256) void k_cast(const float* __restrict__ f,
                                              u16* __restrict__ o) {
    int idx = blockIdx.x * 256 + (int)threadIdx.x;   // one per 8 elements
    if (idx < N_NODES * (D / 8)) {
        const float4* fp = (const float4*)(f + (size_t)idx * 8);
        float4 a = fp[0], b = fp[1];
        uint4 p;
        p.x = (u32)f2b(a.x) | ((u32)f2b(a.y) << 16);
        p.y = (u32)f2b(a.z) | ((u32)f2b(a.w) << 16);
        p.z = (u32)f2b(b.x) | ((u32)f2b(b.y) << 16);
        p.w = (u32)f2b(b.z) | ((u32)f2b(b.w) << 16);
        ((uint4*)o)[idx] = p;
    }
}

// ---------------------------------------------------------------------------
// K5: transpose+cast the 6 weight matrices: W[k][n] f32 -> Wt[n][k] bf16
// grid (4, 6): bx = k-chunk of 32, by = matrix id
// ---------------------------------------------------------------------------
__global__ __launch_bounds__(256) void k_prepw(
        const float* __restrict__ w0, const float* __restrict__ w1,
        const float* __restrict__ w2, const float* __restrict__ w3,
        const float* __restrict__ w4, const float* __restrict__ w5,
        u16* __restrict__ wt) {
    const float* W;
    switch (blockIdx.y) {
        case 0: W = w0; break; case 1: W = w1; break; case 2: W = w2; break;
        case 3: W = w3; break; case 4: W = w4; break; default: W = w5; break;
    }
    u16* out = wt + (size_t)blockIdx.y * D * D;
    int k0 = blockIdx.x * 32;
    __shared__ float s[32][129];
    // stage 32 rows of W (k0..k0+31) x 128 cols, coalesced (32 rows x 32 float4)
    for (int t = threadIdx.x; t < 32 * 32; t += 256) {
        int r = t >> 5, c4 = t & 31;
        float4 v = ((const float4*)&W[(size_t)(k0 + r) * D])[c4];
        s[r][c4 * 4 + 0] = v.x; s[r][c4 * 4 + 1] = v.y;
        s[r][c4 * 4 + 2] = v.z; s[r][c4 * 4 + 3] = v.w;
    }
    __syncthreads();
    // write Wt[n][k0+g*8 .. +8] as 16B chunks: 128 n x 4 groups = 512 chunks
    for (int t = threadIdx.x; t < 512; t += 256) {
        int n = t >> 2, g = t & 3;
        uint4 p;
        p.x = (u32)f2b(s[g * 8 + 0][n]) | ((u32)f2b(s[g * 8 + 1][n]) << 16);
        p.y = (u32)f2b(s[g * 8 + 2][n]) | ((u32)f2b(s[g * 8 + 3][n]) << 16);
        p.z = (u32)f2b(s[g * 8 + 4][n]) | ((u32)f2b(s[g * 8 + 5][n]) << 16);
        p.w = (u32)f2b(s[g * 8 + 6][n]) | ((u32)f2b(s[g * 8 + 7][n]) << 16);
        *(uint4*)&out[(size_t)n * D + k0 + g * 8] = p;
    }
}

// ---------------------------------------------------------------------------
// K6: MFMA GEMM: out = A(bf16) @ W(bf16), f32 acc, bf16 out.
// blockIdx.y==0 -> hs = A@Wself + b ; blockIdx.y==1 -> hn = A@Wneigh
// Block 256 thr = 4 waves in 2x2; block tile M=64 x N=128; full K=128 in LDS.
// Wave: 32 rows x 64 cols = 2 tiles of 32x32, 16 MFMA (32x32x16) each wave.
// NOTE: one float4 = 8 bf16, so a 128-wide row = 16 float4 chunks.
// ---------------------------------------------------------------------------
__global__ __launch_bounds__(256) void k_gemm(
        const u16* __restrict__ A, const u16* __restrict__ Wt_self,
        const u16* __restrict__ Wt_neigh, const float* __restrict__ bias,
        u16* __restrict__ hs, u16* __restrict__ hn) {
    const bool is_self = (blockIdx.y == 0);
    const u16* __restrict__ Wt = is_self ? Wt_self : Wt_neigh;
    u16* __restrict__ outp = is_self ? hs : hn;
    const int row0 = blockIdx.x * 64;

    __shared__ u16 As[64 * LDA];    // 17.0 KB  (row stride 272 B)
    __shared__ u16 Ws[128 * LDA];   // 34.8 KB

    const int tid = (int)threadIdx.x;
    // stage A tile: 64 rows x 128 bf16 = 64 x 16 float4 chunks = 1024
    for (int t = tid; t < 1024; t += 256) {
        int r = t >> 4, c = t & 15;
        int row = row0 + r; if (row >= N_NODES) row = N_NODES - 1;
        *(float4*)&As[r * LDA + c * 8] = ((const float4*)&A[(size_t)row * D])[c];
    }
    // stage Wt: 128 rows x 128 bf16 = 128 x 16 float4 chunks = 2048
    for (int t = tid; t < 2048; t += 256) {
        int r = t >> 4, c = t & 15;
        *(float4*)&Ws[r * LDA + c * 8] = ((const float4*)&Wt[(size_t)r * D])[c];
    }
    __syncthreads();

    const int lane = tid & 63;
    const int wave = tid >> 6;
    const int wm = wave & 1;    // row band (32 rows)
    const int wn = wave >> 1;   // col half (64 cols)
    const int m  = lane & 31;
    const int kh = lane >> 5;   // k-half within 16-chunk

    f32x16 acc0, acc1;
#pragma unroll
    for (int i = 0; i < 16; ++i) { acc0[i] = 0.0f; acc1[i] = 0.0f; }

    const u16* ap  = &As[(wm * 32 + m) * LDA + kh * 8];
    const u16* bp0 = &Ws[(wn * 64 + m) * LDA + kh * 8];
    const u16* bp1 = bp0 + 32 * LDA;
#pragma unroll
    for (int kk = 0; kk < 8; ++kk) {
        bf16x8 a  = *(const bf16x8*)(ap  + kk * 16);
        bf16x8 b0 = *(const bf16x8*)(bp0 + kk * 16);
        bf16x8 b1 = *(const bf16x8*)(bp1 + kk * 16);
        acc0 = __builtin_amdgcn_mfma_f32_32x32x16_bf16(a, b0, acc0, 0, 0, 0);
        acc1 = __builtin_amdgcn_mfma_f32_32x32x16_bf16(a, b1, acc1, 0, 0, 0);
    }

    // epilogue: C/D layout: col = lane&31, row = (r&3) + 8*(r>>2) + 4*(lane>>5)
    const int c0 = wn * 64 + m;
    const int c1 = c0 + 32;
    const float b0v = is_self ? bias[c0] : 0.0f;
    const float b1v = is_self ? bias[c1] : 0.0f;
#pragma unroll
    for (int r = 0; r < 16; ++r) {
        int rowl = (r & 3) + 8 * (r >> 2) + 4 * kh;
        int grow = row0 + wm * 32 + rowl;
        if (grow < N_NODES) {
            outp[(size_t)grow * D + c0] = f2b(acc0[r] + b0v);
            outp[(size_t)grow * D + c1] = f2b(acc1[r] + b1v);
        }
    }
}

// ---------------------------------------------------------------------------
// K7: aggregate: out[v] = act( hs[v] + rcp[v] * sum_{u in csr(v)} hn[u] )
// One wave/node; quad q handles neighbor j=beg+q (4 nbrs/iter, unroll x2);
// 16 lanes x 16B (8 bf16) per neighbor row. f32 accumulate; shfl-xor reduce.
// ---------------------------------------------------------------------------
__global__ __launch_bounds__(256) void k_agg(
        const u16* __restrict__ hs, const u16* __restrict__ hn,
        const int* __restrict__ row_off, const int* __restrict__ csr,
        const float* __restrict__ rcp, void* __restrict__ outp, int final_f32) {
    int v = blockIdx.x * 4 + (int)(threadIdx.x >> 6);
    if (v >= N_NODES) return;
    int lane = (int)threadIdx.x & 63;
    int q = lane >> 4, cl = lane & 15;
    int beg = row_off[v], end = row_off[v + 1];

    float ax[8];
#pragma unroll
    for (int i = 0; i < 8; ++i) ax[i] = 0.0f;

    int j = beg + q;
    for (; j + 4 < end; j += 8) {
        int u0 = csr[j], u1 = csr[j + 4];
        bf16x8 x0 = *(const bf16x8*)&hn[(size_t)u0 * D + cl * 8];
        bf16x8 x1 = *(const bf16x8*)&hn[(size_t)u1 * D + cl * 8];
#pragma unroll
        for (int i = 0; i < 8; ++i)
            ax[i] += b2f((u16)x0[i]) + b2f((u16)x1[i]);
    }
    if (j < end) {
        int u0 = csr[j];
        bf16x8 x0 = *(const bf16x8*)&hn[(size_t)u0 * D + cl * 8];
#pragma unroll
        for (int i = 0; i < 8; ++i) ax[i] += b2f((u16)x0[i]);
    }
    // reduce across the 4 quads
#pragma unroll
    for (int i = 0; i < 8; ++i) {
        ax[i] += __shfl_xor(ax[i], 16);
        ax[i] += __shfl_xor(ax[i], 32);
    }
    if (lane < 16) {
        float r = rcp[v];
        bf16x8 sv = *(const bf16x8*)&hs[(size_t)v * D + cl * 8];
        float o[8];
#pragma unroll
        for (int i = 0; i < 8; ++i) o[i] = fmaf(ax[i], r, b2f((u16)sv[i]));
        if (!final_f32) {
#pragma unroll
            for (int i = 0; i < 8; ++i) o[i] = fmaxf(o[i], 0.0f);
            uint4 p;
            p.x = (u32)f2b(o[0]) | ((u32)f2b(o[1]) << 16);
            p.y = (u32)f2b(o[2]) | ((u32)f2b(o[3]) << 16);
            p.z = (u32)f2b(o[4]) | ((u32)f2b(o[5]) << 16);
            p.w = (u32)f2b(o[6]) | ((u32)f2b(o[7]) << 16);
            *(uint4*)&((u16*)outp)[(size_t)v * D + cl * 8] = p;
        } else {
            float* of = (float*)outp;
            float4 p0 = {o[0], o[1], o[2], o[3]};
            float4 p1 = {o[4], o[5], o[6], o[7]};
            ((float4*)&of[(size_t)v * D + cl * 8])[0] = p0;
            ((float4*)&of[(size_t)v * D + cl * 8])[1] = p1;
        }
    }
}

// ---------------------------------------------------------------------------
extern "C" void kernel_launch(void* const* d_in, const int* in_sizes, int n_in,
                              void* d_out, int out_size, void* d_ws, size_t ws_size,
                              hipStream_t stream) {
    const float* features = (const float*)d_in[0];
    const int*   edge_src = (const int*)d_in[1];
    const int*   edge_dst = (const int*)d_in[2];
    const float* Wself[3] = {(const float*)d_in[3], (const float*)d_in[6], (const float*)d_in[9]};
    const float* Wngh[3]  = {(const float*)d_in[4], (const float*)d_in[7], (const float*)d_in[10]};
    const float* bias[3]  = {(const float*)d_in[5], (const float*)d_in[8], (const float*)d_in[11]};
    float* out = (float*)d_out;

    char* ws = (char*)d_ws;
    size_t off = 0;
    auto alloc = [&](size_t bytes) {
        char* p = ws + off;
        off += (bytes + 255) & ~(size_t)255;
        return p;
    };
    int*   deg     = (int*)alloc(N_NODES * sizeof(int));
    int*   fill    = (int*)alloc(N_NODES * sizeof(int));
    int*   row_off = (int*)alloc((N_NODES + 1) * sizeof(int));
    float* rcp     = (float*)alloc(N_NODES * sizeof(float));
    int*   csr     = (int*)alloc(N_EDGES * sizeof(int));
    u16*   hs      = (u16*)alloc((size_t)N_NODES * D * sizeof(u16));
    u16*   hn      = (u16*)alloc((size_t)N_NODES * D * sizeof(u16));
    u16*   hb0     = (u16*)alloc((size_t)N_NODES * D * sizeof(u16));
    u16*   hb1     = (u16*)alloc((size_t)N_NODES * D * sizeof(u16));
    u16*   wt      = (u16*)alloc((size_t)6 * D * D * sizeof(u16));
    int*   partial = (int*)alloc(NB * sizeof(int));
    int*   ppref   = (int*)alloc(NB * sizeof(int));

    hipMemsetAsync(deg, 0, ((N_NODES * sizeof(int) + 255) & ~(size_t)255) * 2, stream);

    // CSR build
    k_degree<<<(N_EDGES + 255) / 256, 256, 0, stream>>>(edge_dst, deg);
    k_scan1<<<NB, 256, 0, stream>>>(deg, row_off, partial, rcp);
    k_scan2<<<1, 256, 0, stream>>>(partial, ppref);
    k_scan3<<<NB, 256, 0, stream>>>(row_off, ppref);
    k_fill<<<(N_EDGES + 255) / 256, 256, 0, stream>>>(edge_src, edge_dst, row_off, fill, csr);

    // bf16 prep
    k_cast<<<(N_NODES * (D / 8) + 255) / 256, 256, 0, stream>>>(features, hb0);
    k_prepw<<<dim3(4, 6), 256, 0, stream>>>(Wself[0], Wngh[0], Wself[1], Wngh[1],
                                            Wself[2], Wngh[2], wt);

    const int gemm_gx = (N_NODES + 63) / 64;
    const int agg_gx  = (N_NODES + 3) / 4;
    const size_t WSZ = (size_t)D * D;

    // layer 0: hb0 -> hb1 (relu)
    k_gemm<<<dim3(gemm_gx, 2), 256, 0, stream>>>(hb0, wt + 0 * WSZ, wt + 1 * WSZ, bias[0], hs, hn);
    k_agg<<<agg_gx, 256, 0, stream>>>(hs, hn, row_off, csr, rcp, hb1, 0);
    // layer 1: hb1 -> hb0 (relu)
    k_gemm<<<dim3(gemm_gx, 2), 256, 0, stream>>>(hb1, wt + 2 * WSZ, wt + 3 * WSZ, bias[1], hs, hn);
    k_agg<<<agg_gx, 256, 0, stream>>>(hs, hn, row_off, csr, rcp, hb0, 0);
    // layer 2: hb0 -> out (f32, no act)
    k_gemm<<<dim3(gemm_gx, 2), 256, 0, stream>>>(hb0, wt + 4 * WSZ, wt + 5 * WSZ, bias[2], hs, hn);
    k_agg<<<agg_gx, 256, 0, stream>>>(hs, hn, row_off, csr, rcp, out, 1);
}

// Round 5
// 308.303 us; speedup vs baseline: 2.1767x; 1.1521x over previous
//
#include <hip/hip_runtime.h>

#define N_NODES 50000
#define N_EDGES 800000
#define D 128
#define NBKT ((N_NODES + 255) / 256)   // 196 buckets of 256 nodes
#define EPB 2048                       // edges per k_part block
#define LDA 136                        // LDS row stride in ushorts (128 + 8 pad)

typedef unsigned short u16;
typedef unsigned int   u32;
typedef short bf16x8 __attribute__((ext_vector_type(8)));
typedef float f32x16 __attribute__((ext_vector_type(16)));

// f32 -> bf16 (round-to-nearest-even)
__device__ __forceinline__ u16 f2b(float x) {
    union { float f; u32 u; } c; c.f = x;
    u32 r = c.u + 0x7FFFu + ((c.u >> 16) & 1u);
    return (u16)(r >> 16);
}
__device__ __forceinline__ float b2f(u16 u) {
    union { u32 u; float f; } c; c.u = ((u32)u) << 16;
    return c.f;
}

// ---------------------------------------------------------------------------
// B1: bucket histogram (bucket = dst>>8). LDS-staged: 196 global atomics/block.
// ---------------------------------------------------------------------------
__global__ __launch_bounds__(256) void k_bhist(const int* __restrict__ dst,
                                               int* __restrict__ gbh) {
    __shared__ int h[NBKT];
    for (int t = threadIdx.x; t < NBKT; t += 256) h[t] = 0;
    __syncthreads();
    int base = blockIdx.x * 1024;
#pragma unroll
    for (int j = 0; j < 4; ++j) {
        int e = base + j * 256 + (int)threadIdx.x;
        if (e < N_EDGES) atomicAdd(&h[dst[e] >> 8], 1);
    }
    __syncthreads();
    for (int t = threadIdx.x; t < NBKT; t += 256)
        if (h[t]) atomicAdd(&gbh[t], h[t]);
}

// ---------------------------------------------------------------------------
// B2: scan 196 bucket totals -> bucket_off[NBKT+1]; also row_off[N]=E.
// ---------------------------------------------------------------------------
__global__ __launch_bounds__(256) void k_bscan(const int* __restrict__ gbh,
                                               int* __restrict__ boff,
                                               int* __restrict__ row_off) {
    __shared__ int s[256];
    int v = ((int)threadIdx.x < NBKT) ? gbh[threadIdx.x] : 0;
    s[threadIdx.x] = v;
    __syncthreads();
#pragma unroll
    for (int off = 1; off < 256; off <<= 1) {
        int t = (threadIdx.x >= (unsigned)off) ? s[threadIdx.x - off] : 0;
        __syncthreads();
        s[threadIdx.x] += t;
        __syncthreads();
    }
    if ((int)threadIdx.x < NBKT) boff[threadIdx.x] = s[threadIdx.x] - v;
    if (threadIdx.x == 0) { boff[NBKT] = N_EDGES; row_off[N_NODES] = N_EDGES; }
}

// ---------------------------------------------------------------------------
// B3: partition edges into bucket-contiguous ebuf. Per-block chunk reservation:
// one global atomic per bucket per block; writes are contiguous chunks.
// Record: u32 = src (16b) | local_node (8b) << 16.
// ---------------------------------------------------------------------------
__global__ __launch_bounds__(256) void k_part(const int* __restrict__ src,
                                              const int* __restrict__ dst,
                                              const int* __restrict__ boff,
                                              int* __restrict__ gbfill,
                                              u32* __restrict__ ebuf) {
    __shared__ u16 ls[EPB], ld_[EPB];
    __shared__ int hist[NBKT], lcnt[NBKT], basev[NBKT];
    const int e0 = blockIdx.x * EPB;
    for (int t = threadIdx.x; t < NBKT; t += 256) { hist[t] = 0; lcnt[t] = 0; }
    __syncthreads();
#pragma unroll
    for (int j = 0; j < EPB / 256; ++j) {
        int t = j * 256 + (int)threadIdx.x;
        int e = e0 + t;
        if (e < N_EDGES) {
            int d = dst[e];
            ls[t] = (u16)src[e];
            ld_[t] = (u16)d;
            atomicAdd(&hist[d >> 8], 1);
        }
    }
    __syncthreads();
    for (int t = threadIdx.x; t < NBKT; t += 256)
        basev[t] = boff[t] + (hist[t] ? atomicAdd(&gbfill[t], hist[t]) : 0);
    __syncthreads();
#pragma unroll
    for (int j = 0; j < EPB / 256; ++j) {
        int t = j * 256 + (int)threadIdx.x;
        int e = e0 + t;
        if (e < N_EDGES) {
            int d = (int)ld_[t];
            int b = d >> 8;
            int o = atomicAdd(&lcnt[b], 1);
            ebuf[basev[b] + o] = (u32)ls[t] | ((u32)(d & 255) << 16);
        }
    }
}

// ---------------------------------------------------------------------------
// B4: per-bucket build: LDS degree hist + scan -> row_off/rcp (coalesced),
// then csr fill (u16 src) within the bucket's contiguous window.
// ---------------------------------------------------------------------------
__global__ __launch_bounds__(256) void k_build(const u32* __restrict__ ebuf,
                                               const int* __restrict__ boff,
                                               int* __restrict__ row_off,
                                               float* __restrict__ rcp,
                                               u16* __restrict__ csr) {
    __shared__ int dcnt[256], fcnt[256], sdata[256];
    const int b = blockIdx.x;
    const int beg = boff[b], end = boff[b + 1];
    dcnt[threadIdx.x] = 0;
    fcnt[threadIdx.x] = 0;
    __syncthreads();
    for (int j = beg + (int)threadIdx.x; j < end; j += 256)
        atomicAdd(&dcnt[(ebuf[j] >> 16) & 255], 1);
    __syncthreads();
    int v = dcnt[threadIdx.x];
    sdata[threadIdx.x] = v;
    __syncthreads();
#pragma unroll
    for (int off = 1; off < 256; off <<= 1) {
        int t = (threadIdx.x >= (unsigned)off) ? sdata[threadIdx.x - off] : 0;
        __syncthreads();
        sdata[threadIdx.x] += t;
        __syncthreads();
    }
    int node = (b << 8) + (int)threadIdx.x;
    if (node < N_NODES) {
        row_off[node] = beg + sdata[threadIdx.x] - v;   // exclusive prefix
        rcp[node] = 1.0f / (float)max(v, 1);
    }
    for (int j = beg + (int)threadIdx.x; j < end; j += 256) {
        u32 u = ebuf[j];
        int ln = (u >> 16) & 255;
        int o = atomicAdd(&fcnt[ln], 1);
        csr[beg + (sdata[ln] - dcnt[ln]) + o] = (u16)(u & 0xFFFFu);
    }
}

// ---------------------------------------------------------------------------
// K4: cast features f32 -> bf16 (8 elems/thread)
// ---------------------------------------------------------------------------
__global__ __launch_bounds__(256) void k_cast(const float* __restrict__ f,
                                              u16* __restrict__ o) {
    int idx = blockIdx.x * 256 + (int)threadIdx.x;
    if (idx < N_NODES * (D / 8)) {
        const float4* fp = (const float4*)(f + (size_t)idx * 8);
        float4 a = fp[0], b = fp[1];
        uint4 p;
        p.x = (u32)f2b(a.x) | ((u32)f2b(a.y) << 16);
        p.y = (u32)f2b(a.z) | ((u32)f2b(a.w) << 16);
        p.z = (u32)f2b(b.x) | ((u32)f2b(b.y) << 16);
        p.w = (u32)f2b(b.z) | ((u32)f2b(b.w) << 16);
        ((uint4*)o)[idx] = p;
    }
}

// ---------------------------------------------------------------------------
// K5: transpose+cast the 6 weight matrices: W[k][n] f32 -> Wt[n][k] bf16
// ---------------------------------------------------------------------------
__global__ __launch_bounds__(256) void k_prepw(
        const float* __restrict__ w0, const float* __restrict__ w1,
        const float* __restrict__ w2, const float* __restrict__ w3,
        const float* __restrict__ w4, const float* __restrict__ w5,
        u16* __restrict__ wt) {
    const float* W;
    switch (blockIdx.y) {
        case 0: W = w0; break; case 1: W = w1; break; case 2: W = w2; break;
        case 3: W = w3; break; case 4: W = w4; break; default: W = w5; break;
    }
    u16* out = wt + (size_t)blockIdx.y * D * D;
    int k0 = blockIdx.x * 32;
    __shared__ float s[32][129];
    for (int t = threadIdx.x; t < 32 * 32; t += 256) {
        int r = t >> 5, c4 = t & 31;
        float4 v = ((const float4*)&W[(size_t)(k0 + r) * D])[c4];
        s[r][c4 * 4 + 0] = v.x; s[r][c4 * 4 + 1] = v.y;
        s[r][c4 * 4 + 2] = v.z; s[r][c4 * 4 + 3] = v.w;
    }
    __syncthreads();
    for (int t = threadIdx.x; t < 512; t += 256) {
        int n = t >> 2, g = t & 3;
        uint4 p;
        p.x = (u32)f2b(s[g * 8 + 0][n]) | ((u32)f2b(s[g * 8 + 1][n]) << 16);
        p.y = (u32)f2b(s[g * 8 + 2][n]) | ((u32)f2b(s[g * 8 + 3][n]) << 16);
        p.z = (u32)f2b(s[g * 8 + 4][n]) | ((u32)f2b(s[g * 8 + 5][n]) << 16);
        p.w = (u32)f2b(s[g * 8 + 6][n]) | ((u32)f2b(s[g * 8 + 7][n]) << 16);
        *(uint4*)&out[(size_t)n * D + k0 + g * 8] = p;
    }
}

// ---------------------------------------------------------------------------
// K6: MFMA GEMM: out = A(bf16) @ W(bf16), f32 acc, bf16 out.
// Block 256 thr = 4 waves in 2x2; block tile M=64 x N=128; full K=128 in LDS.
// ---------------------------------------------------------------------------
__global__ __launch_bounds__(256) void k_gemm(
        const u16* __restrict__ A, const u16* __restrict__ Wt_self,
        const u16* __restrict__ Wt_neigh, const float* __restrict__ bias,
        u16* __restrict__ hs, u16* __restrict__ hn) {
    const bool is_self = (blockIdx.y == 0);
    const u16* __restrict__ Wt = is_self ? Wt_self : Wt_neigh;
    u16* __restrict__ outp = is_self ? hs : hn;
    const int row0 = blockIdx.x * 64;

    __shared__ u16 As[64 * LDA];
    __shared__ u16 Ws[128 * LDA];

    const int tid = (int)threadIdx.x;
    for (int t = tid; t < 1024; t += 256) {        // 64 rows x 16 chunks
        int r = t >> 4, c = t & 15;
        int row = row0 + r; if (row >= N_NODES) row = N_NODES - 1;
        *(float4*)&As[r * LDA + c * 8] = ((const float4*)&A[(size_t)row * D])[c];
    }
    for (int t = tid; t < 2048; t += 256) {        // 128 rows x 16 chunks
        int r = t >> 4, c = t & 15;
        *(float4*)&Ws[r * LDA + c * 8] = ((const float4*)&Wt[(size_t)r * D])[c];
    }
    __syncthreads();

    const int lane = tid & 63;
    const int wave = tid >> 6;
    const int wm = wave & 1;
    const int wn = wave >> 1;
    const int m  = lane & 31;
    const int kh = lane >> 5;

    f32x16 acc0, acc1;
#pragma unroll
    for (int i = 0; i < 16; ++i) { acc0[i] = 0.0f; acc1[i] = 0.0f; }

    const u16* ap  = &As[(wm * 32 + m) * LDA + kh * 8];
    const u16* bp0 = &Ws[(wn * 64 + m) * LDA + kh * 8];
    const u16* bp1 = bp0 + 32 * LDA;
#pragma unroll
    for (int kk = 0; kk < 8; ++kk) {
        bf16x8 a  = *(const bf16x8*)(ap  + kk * 16);
        bf16x8 b0 = *(const bf16x8*)(bp0 + kk * 16);
        bf16x8 b1 = *(const bf16x8*)(bp1 + kk * 16);
        acc0 = __builtin_amdgcn_mfma_f32_32x32x16_bf16(a, b0, acc0, 0, 0, 0);
        acc1 = __builtin_amdgcn_mfma_f32_32x32x16_bf16(a, b1, acc1, 0, 0, 0);
    }

    const int c0 = wn * 64 + m;
    const int c1 = c0 + 32;
    const float b0v = is_self ? bias[c0] : 0.0f;
    const float b1v = is_self ? bias[c1] : 0.0f;
#pragma unroll
    for (int r = 0; r < 16; ++r) {
        int rowl = (r & 3) + 8 * (r >> 2) + 4 * kh;
        int grow = row0 + wm * 32 + rowl;
        if (grow < N_NODES) {
            outp[(size_t)grow * D + c0] = f2b(acc0[r] + b0v);
            outp[(size_t)grow * D + c1] = f2b(acc1[r] + b1v);
        }
    }
}

// ---------------------------------------------------------------------------
// K7: aggregate: out[v] = act( hs[v] + rcp[v] * sum_{u in csr(v)} hn[u] )
// One wave/node; quad q handles neighbor j=beg+q; csr is u16.
// ---------------------------------------------------------------------------
__global__ __launch_bounds__(256) void k_agg(
        const u16* __restrict__ hs, const u16* __restrict__ hn,
        const int* __restrict__ row_off, const u16* __restrict__ csr,
        const float* __restrict__ rcp, void* __restrict__ outp, int final_f32) {
    int v = blockIdx.x * 4 + (int)(threadIdx.x >> 6);
    if (v >= N_NODES) return;
    int lane = (int)threadIdx.x & 63;
    int q = lane >> 4, cl = lane & 15;
    int beg = row_off[v], end = row_off[v + 1];

    float ax[8];
#pragma unroll
    for (int i = 0; i < 8; ++i) ax[i] = 0.0f;

    int j = beg + q;
    for (; j + 4 < end; j += 8) {
        int u0 = csr[j], u1 = csr[j + 4];
        bf16x8 x0 = *(const bf16x8*)&hn[(size_t)u0 * D + cl * 8];
        bf16x8 x1 = *(const bf16x8*)&hn[(size_t)u1 * D + cl * 8];
#pragma unroll
        for (int i = 0; i < 8; ++i)
            ax[i] += b2f((u16)x0[i]) + b2f((u16)x1[i]);
    }
    if (j < end) {
        int u0 = csr[j];
        bf16x8 x0 = *(const bf16x8*)&hn[(size_t)u0 * D + cl * 8];
#pragma unroll
        for (int i = 0; i < 8; ++i) ax[i] += b2f((u16)x0[i]);
    }
#pragma unroll
    for (int i = 0; i < 8; ++i) {
        ax[i] += __shfl_xor(ax[i], 16);
        ax[i] += __shfl_xor(ax[i], 32);
    }
    if (lane < 16) {
        float r = rcp[v];
        bf16x8 sv = *(const bf16x8*)&hs[(size_t)v * D + cl * 8];
        float o[8];
#pragma unroll
        for (int i = 0; i < 8; ++i) o[i] = fmaf(ax[i], r, b2f((u16)sv[i]));
        if (!final_f32) {
#pragma unroll
            for (int i = 0; i < 8; ++i) o[i] = fmaxf(o[i], 0.0f);
            uint4 p;
            p.x = (u32)f2b(o[0]) | ((u32)f2b(o[1]) << 16);
            p.y = (u32)f2b(o[2]) | ((u32)f2b(o[3]) << 16);
            p.z = (u32)f2b(o[4]) | ((u32)f2b(o[5]) << 16);
            p.w = (u32)f2b(o[6]) | ((u32)f2b(o[7]) << 16);
            *(uint4*)&((u16*)outp)[(size_t)v * D + cl * 8] = p;
        } else {
            float* of = (float*)outp;
            float4 p0 = {o[0], o[1], o[2], o[3]};
            float4 p1 = {o[4], o[5], o[6], o[7]};
            ((float4*)&of[(size_t)v * D + cl * 8])[0] = p0;
            ((float4*)&of[(size_t)v * D + cl * 8])[1] = p1;
        }
    }
}

// ---------------------------------------------------------------------------
extern "C" void kernel_launch(void* const* d_in, const int* in_sizes, int n_in,
                              void* d_out, int out_size, void* d_ws, size_t ws_size,
                              hipStream_t stream) {
    const float* features = (const float*)d_in[0];
    const int*   edge_src = (const int*)d_in[1];
    const int*   edge_dst = (const int*)d_in[2];
    const float* Wself[3] = {(const float*)d_in[3], (const float*)d_in[6], (const float*)d_in[9]};
    const float* Wngh[3]  = {(const float*)d_in[4], (const float*)d_in[7], (const float*)d_in[10]};
    const float* bias[3]  = {(const float*)d_in[5], (const float*)d_in[8], (const float*)d_in[11]};
    float* out = (float*)d_out;

    char* ws = (char*)d_ws;
    size_t off = 0;
    auto alloc = [&](size_t bytes) {
        char* p = ws + off;
        off += (bytes + 255) & ~(size_t)255;
        return p;
    };
    int*   gcnt    = (int*)alloc(2 * 256 * sizeof(int));   // gbh | gbfill
    int*   gbh     = gcnt;
    int*   gbfill  = gcnt + 256;
    int*   boff    = (int*)alloc((NBKT + 1) * sizeof(int));
    int*   row_off = (int*)alloc((N_NODES + 1) * sizeof(int));
    float* rcp     = (float*)alloc(N_NODES * sizeof(float));
    u32*   ebuf    = (u32*)alloc((size_t)N_EDGES * sizeof(u32));
    u16*   csr     = (u16*)alloc((size_t)N_EDGES * sizeof(u16));
    u16*   hs      = (u16*)alloc((size_t)N_NODES * D * sizeof(u16));
    u16*   hn      = (u16*)alloc((size_t)N_NODES * D * sizeof(u16));
    u16*   hb0     = (u16*)alloc((size_t)N_NODES * D * sizeof(u16));
    u16*   hb1     = (u16*)alloc((size_t)N_NODES * D * sizeof(u16));
    u16*   wt      = (u16*)alloc((size_t)6 * D * D * sizeof(u16));

    hipMemsetAsync(gcnt, 0, 2 * 256 * sizeof(int), stream);

    // CSR build (bucketed)
    k_bhist<<<(N_EDGES + 1023) / 1024, 256, 0, stream>>>(edge_dst, gbh);
    k_bscan<<<1, 256, 0, stream>>>(gbh, boff, row_off);
    k_part<<<(N_EDGES + EPB - 1) / EPB, 256, 0, stream>>>(edge_src, edge_dst, boff, gbfill, ebuf);
    k_build<<<NBKT, 256, 0, stream>>>(ebuf, boff, row_off, rcp, csr);

    // bf16 prep
    k_cast<<<(N_NODES * (D / 8) + 255) / 256, 256, 0, stream>>>(features, hb0);
    k_prepw<<<dim3(4, 6), 256, 0, stream>>>(Wself[0], Wngh[0], Wself[1], Wngh[1],
                                            Wself[2], Wngh[2], wt);

    const int gemm_gx = (N_NODES + 63) / 64;
    const int agg_gx  = (N_NODES + 3) / 4;
    const size_t WSZ = (size_t)D * D;

    // layer 0: hb0 -> hb1 (relu)
    k_gemm<<<dim3(gemm_gx, 2), 256, 0, stream>>>(hb0, wt + 0 * WSZ, wt + 1 * WSZ, bias[0], hs, hn);
    k_agg<<<agg_gx, 256, 0, stream>>>(hs, hn, row_off, csr, rcp, hb1, 0);
    // layer 1: hb1 -> hb0 (relu)
    k_gemm<<<dim3(gemm_gx, 2), 256, 0, stream>>>(hb1, wt + 2 * WSZ, wt + 3 * WSZ, bias[1], hs, hn);
    k_agg<<<agg_gx, 256, 0, stream>>>(hs, hn, row_off, csr, rcp, hb0, 0);
    // layer 2: hb0 -> out (f32, no act)
    k_gemm<<<dim3(gemm_gx, 2), 256, 0, stream>>>(hb0, wt + 4 * WSZ, wt + 5 * WSZ, bias[2], hs, hn);
    k_agg<<<agg_gx, 256, 0, stream>>>(hs, hn, row_off, csr, rcp, out, 1);
}